// Round 13
// baseline (1424.379 us; speedup 1.0000x reference)
//
#include <hip/hip_runtime.h>

#define TT 512
#define BB 32
#define DD 64
#define HH 128
#define EE 256
#define NR 16384   // T*B rows

typedef short bf16x8 __attribute__((ext_vector_type(8)));
typedef float f32x4 __attribute__((ext_vector_type(4)));

// ---------- helpers ----------
static __device__ __forceinline__ float bflo(unsigned u){ return __uint_as_float(u << 16); }
static __device__ __forceinline__ float bfhi(unsigned u){ return __uint_as_float(u & 0xFFFF0000u); }
static __device__ __forceinline__ unsigned short f2bf(float x){
  unsigned u = __float_as_uint(x);
  return (unsigned short)((u + 0x7FFFu + ((u >> 16) & 1u)) >> 16);  // RNE
}
static __device__ __forceinline__ unsigned packbf(float a, float b){
  return (unsigned)f2bf(a) | ((unsigned)f2bf(b) << 16);
}
static __device__ __forceinline__ float sigmoidf_(float x){
  return 1.0f / (1.0f + __expf(-x));
}
static __device__ __forceinline__ float tanhf_(float x){
  float e = __expf(2.0f * x);
  return 1.0f - 2.0f / (e + 1.0f);
}
// LDS-only barrier: don't drain vmcnt (gi prefetch / hc stores stay in flight)
#define LGKM_BARRIER() asm volatile("s_waitcnt lgkmcnt(0)\n\ts_barrier" ::: "memory")

// load a B-fragment (8 consecutive f32 -> bf16x8) from a weight row
static __device__ __forceinline__ bf16x8 ldwfrag(const float* p){
  float4 u = *(const float4*)p;
  float4 v = *(const float4*)(p + 4);
  uint4 q;
  q.x = packbf(u.x, u.y); q.y = packbf(u.z, u.w);
  q.z = packbf(v.x, v.y); q.w = packbf(v.z, v.w);
  return __builtin_bit_cast(bf16x8, q);
}

// ---------- K1: MFMA gi. gi[r][c] = bi + xm[r] . Wi_row(c), c in [0,768) (fwd|bwd) ----------
__global__ __launch_bounds__(256) void gi_mfma_kernel(
    const float* __restrict__ x, const float* __restrict__ mask,
    const float* __restrict__ WiF, const float* __restrict__ biF,
    const float* __restrict__ WiB, const float* __restrict__ biB,
    float* __restrict__ gi)
{
  __shared__ unsigned short As[64*72];
  __shared__ unsigned short Ws[64*72];
  int tid = threadIdx.x;
  int r0 = blockIdx.x * 64;
  int lane = tid & 63;
  int w = tid >> 6;
  int lr = lane & 15, lk = lane >> 4;

#pragma unroll
  for (int it = 0; it < 4; ++it) {
    int l = tid + it*256;
    int row = l >> 4, kq = l & 15;
    int r = r0 + row; int t = r >> 5, b = r & 31;
    const float* xr = x + ((size_t)b*TT + t)*DD + kq*4;
    const float* mr = mask + ((size_t)b*TT + t)*DD + kq*4;
    float4 xv = *(const float4*)xr;
    float4 mv = *(const float4*)mr;
    unsigned* dst = (unsigned*)&As[row*72 + kq*4];
    dst[0] = packbf(xv.x*mv.x, xv.y*mv.y);
    dst[1] = packbf(xv.z*mv.z, xv.w*mv.w);
  }

  for (int ch = 0; ch < 12; ++ch) {
    int c0 = ch * 64;
    __syncthreads();
#pragma unroll
    for (int it = 0; it < 4; ++it) {
      int l = tid + it*256;
      int col = l >> 4, kq = l & 15;
      int c = c0 + col;
      const float* wr = (c < 384 ? WiF + (size_t)c*64 : WiB + (size_t)(c-384)*64) + kq*4;
      float4 v = *(const float4*)wr;
      unsigned* dst = (unsigned*)&Ws[col*72 + kq*4];
      dst[0] = packbf(v.x, v.y);
      dst[1] = packbf(v.z, v.w);
    }
    __syncthreads();

    const unsigned short* arow = &As[(w*16 + lr)*72 + lk*8];
    f32x4 acc[4];
#pragma unroll
    for (int ct = 0; ct < 4; ++ct) {
      int cg = c0 + ct*16 + lr;
      float bv = (cg < 384) ? biF[cg] : biB[cg - 384];
      acc[ct][0] = bv; acc[ct][1] = bv; acc[ct][2] = bv; acc[ct][3] = bv;
    }
#pragma unroll
    for (int ks = 0; ks < 2; ++ks) {
      bf16x8 a = *(const bf16x8*)(arow + ks*32);
#pragma unroll
      for (int ct = 0; ct < 4; ++ct) {
        bf16x8 wv = *(const bf16x8*)&Ws[(ct*16 + lr)*72 + lk*8 + ks*32];
        acc[ct] = __builtin_amdgcn_mfma_f32_16x16x32_bf16(a, wv, acc[ct], 0, 0, 0);
      }
    }
#pragma unroll
    for (int ct = 0; ct < 4; ++ct) {
#pragma unroll
      for (int j = 0; j < 4; ++j) {
        int row = r0 + w*16 + lk*4 + j;
        gi[(size_t)row*768 + c0 + ct*16 + lr] = acc[ct][j];
      }
    }
  }
}

// ---------- K2: batched MFMA GRU scan. 4 WGs = 2 dir x 2 batch-halves, 256 thr. ----------
// Per step: stage1 H[16][128]@Wrz^T -> r|z (64 MFMA, waves 0-1 r / 2-3 z);
// stage2 rh[16][128]@Whn^T -> n (32 MFMA). Weights = register B-frags.
// h kept in LDS as bf16 A-layout [16][136] + f32 D-layout [16][132].
__global__ __launch_bounds__(256)
__attribute__((amdgpu_waves_per_eu(1, 1)))
void scan_mfma_kernel(
    const float* __restrict__ gi,      // [16384][768]
    const float* __restrict__ WhF, const float* __restrict__ bhF,
    const float* __restrict__ WhB, const float* __restrict__ bhB,
    float* __restrict__ hc)
{
  int dir = blockIdx.x >> 1;
  int bhalf = blockIdx.x & 1;
  const float* Wh = dir ? WhB : WhF;
  const float* bh = dir ? bhB : bhF;
  int tid = threadIdx.x;
  int lane = tid & 63;
  int w = tid >> 6;                 // wave 0..3
  int lr = lane & 15, lk = lane >> 4;

  __shared__ unsigned short h16[16*136];   // bf16 h, A-layout rows=batch (stride 136 u16 = 272B)
  __shared__ unsigned short rh16[16*136];  // bf16 r*h
  __shared__ float hf[16*132];             // f32 h, D-layout access
  __shared__ float zf[16*132];             // f32 z

  // ---- register-resident weight B-fragments ----
  bf16x8 WB1[4][4];                 // stage1: wave tiles (w*4+ct), cols 0..255 of Wh_rz
#pragma unroll
  for (int ct = 0; ct < 4; ++ct)
#pragma unroll
    for (int ks = 0; ks < 4; ++ks)
      WB1[ct][ks] = ldwfrag(Wh + (size_t)((w*4+ct)*16 + lr)*128 + ks*32 + lk*8);
  bf16x8 WB2[2][4];                 // stage2: n-tiles (w*2+ti), Wh rows 256+ncol
#pragma unroll
  for (int ti = 0; ti < 2; ++ti)
#pragma unroll
    for (int ks = 0; ks < 4; ++ks)
      WB2[ti][ks] = ldwfrag(Wh + (size_t)(256 + w*32 + ti*16 + lr)*128 + ks*32 + lk*8);

  float bh1[4], bh2[2];
#pragma unroll
  for (int ct = 0; ct < 4; ++ct) bh1[ct] = bh[(w*4+ct)*16 + lr];
#pragma unroll
  for (int ti = 0; ti < 2; ++ti) bh2[ti] = bh[256 + w*32 + ti*16 + lr];

  for (int l = tid; l < 16*136; l += 256) { h16[l] = 0; rh16[l] = 0; }
  for (int l = tid; l < 16*132; l += 256) { hf[l] = 0.0f; zf[l] = 0.0f; }
  __syncthreads();

  long dstep = (dir ? -(long)BB : (long)BB) * 768;
  int t0_ = dir ? (TT-1) : 0;
  const float* grow = gi + (size_t)(t0_*BB + bhalf*16) * 768 + dir*384;

  // current-step gi (D-layout positions)
  float g1[4][4], g2[2][4];
#pragma unroll
  for (int ct = 0; ct < 4; ++ct)
#pragma unroll
    for (int j = 0; j < 4; ++j)
      g1[ct][j] = grow[(size_t)(lk*4+j)*768 + (w*4+ct)*16 + lr];
#pragma unroll
  for (int ti = 0; ti < 2; ++ti)
#pragma unroll
    for (int j = 0; j < 4; ++j)
      g2[ti][j] = grow[(size_t)(lk*4+j)*768 + 256 + w*32 + ti*16 + lr];

  for (int s = 0; s < TT; ++s) {
    int t = dir ? (TT - 1 - s) : s;
    const float* gnext = grow + dstep;

    // prefetch next step's gi
    float g1n[4][4], g2n[2][4];
    if (s + 1 < TT) {
#pragma unroll
      for (int ct = 0; ct < 4; ++ct)
#pragma unroll
        for (int j = 0; j < 4; ++j)
          g1n[ct][j] = gnext[(size_t)(lk*4+j)*768 + (w*4+ct)*16 + lr];
#pragma unroll
      for (int ti = 0; ti < 2; ++ti)
#pragma unroll
        for (int j = 0; j < 4; ++j)
          g2n[ti][j] = gnext[(size_t)(lk*4+j)*768 + 256 + w*32 + ti*16 + lr];
    } else {
#pragma unroll
      for (int ct = 0; ct < 4; ++ct)
#pragma unroll
        for (int j = 0; j < 4; ++j) g1n[ct][j] = 0.f;
#pragma unroll
      for (int ti = 0; ti < 2; ++ti)
#pragma unroll
        for (int j = 0; j < 4; ++j) g2n[ti][j] = 0.f;
    }

    // ---- stage 1: rz = H @ Wrz^T (+gi+bh) ----
    bf16x8 af[4];
#pragma unroll
    for (int ks = 0; ks < 4; ++ks)
      af[ks] = *(const bf16x8*)&h16[lr*136 + ks*32 + lk*8];

#pragma unroll
    for (int ct = 0; ct < 4; ++ct) {
      f32x4 acc;
      acc[0] = g1[ct][0] + bh1[ct];
      acc[1] = g1[ct][1] + bh1[ct];
      acc[2] = g1[ct][2] + bh1[ct];
      acc[3] = g1[ct][3] + bh1[ct];
#pragma unroll
      for (int ks = 0; ks < 4; ++ks)
        acc = __builtin_amdgcn_mfma_f32_16x16x32_bf16(af[ks], WB1[ct][ks], acc, 0, 0, 0);
      if (w < 2) {
        // r region: cols w*64 + ct*16 + lr in [0,128)
#pragma unroll
        for (int j = 0; j < 4; ++j) {
          int row = lk*4 + j;
          int col = w*64 + ct*16 + lr;
          float rv = sigmoidf_(acc[j]);
          float ho = hf[row*132 + col];
          rh16[row*136 + col] = f2bf(rv * ho);
        }
      } else {
        // z region: cols (w-2)*64 + ct*16 + lr in [0,128)
#pragma unroll
        for (int j = 0; j < 4; ++j) {
          int row = lk*4 + j;
          int col = (w-2)*64 + ct*16 + lr;
          zf[row*132 + col] = sigmoidf_(acc[j]);
        }
      }
    }
    LGKM_BARRIER();   // rh/z visible

    // ---- stage 2: n = rh @ Whn^T (+gi+bh); h_new = n + z*(h-n) ----
    bf16x8 ar[4];
#pragma unroll
    for (int ks = 0; ks < 4; ++ks)
      ar[ks] = *(const bf16x8*)&rh16[lr*136 + ks*32 + lk*8];

#pragma unroll
    for (int ti = 0; ti < 2; ++ti) {
      f32x4 acc;
      acc[0] = g2[ti][0] + bh2[ti];
      acc[1] = g2[ti][1] + bh2[ti];
      acc[2] = g2[ti][2] + bh2[ti];
      acc[3] = g2[ti][3] + bh2[ti];
#pragma unroll
      for (int ks = 0; ks < 4; ++ks)
        acc = __builtin_amdgcn_mfma_f32_16x16x32_bf16(ar[ks], WB2[ti][ks], acc, 0, 0, 0);
#pragma unroll
      for (int j = 0; j < 4; ++j) {
        int row = lk*4 + j;
        int col = w*32 + ti*16 + lr;
        float nn = tanhf_(acc[j]);
        float zv = zf[row*132 + col];
        float ho = hf[row*132 + col];
        float hn = nn + zv * (ho - nn);
        hf[row*132 + col] = hn;
        h16[row*136 + col] = f2bf(hn);
        hc[((size_t)t*BB + bhalf*16 + row) * EE + dir*HH + col] = hn;
      }
    }
    LGKM_BARRIER();   // h visible

#pragma unroll
    for (int ct = 0; ct < 4; ++ct)
#pragma unroll
      for (int j = 0; j < 4; ++j) g1[ct][j] = g1n[ct][j];
#pragma unroll
    for (int ti = 0; ti < 2; ++ti)
#pragma unroll
      for (int j = 0; j < 4; ++j) g2[ti][j] = g2n[ti][j];
    grow = gnext;
  }
}

// ---------- K3: MFMA GEMM. C[r][c] = bias[c] + sum_k A[r][k]*W[c][k], K=256 ----------
__global__ __launch_bounds__(256) void mfma_gemm_kernel(
    const float* __restrict__ A, const float* __restrict__ W,
    const float* __restrict__ bias, float* __restrict__ C,
    int N)
{
  __shared__ unsigned short As[64*264];
  __shared__ unsigned short Ws[64*264];
  int tid = threadIdx.x;
  int r0 = blockIdx.x * 64;
  int lane = tid & 63;
  int w = tid >> 6;
  int lr = lane & 15;
  int lk = lane >> 4;

#pragma unroll
  for (int it = 0; it < 16; ++it) {
    int l = tid + it*256;
    int row = l >> 6, kq = l & 63;
    float4 v = *(const float4*)(A + (size_t)(r0+row)*256 + kq*4);
    unsigned* dst = (unsigned*)&As[row*264 + kq*4];
    dst[0] = packbf(v.x, v.y);
    dst[1] = packbf(v.z, v.w);
  }

  const unsigned short* arow = &As[(w*16 + lr)*264 + lk*8];
  const unsigned short* wrow0 = &Ws[(0*16 + lr)*264 + lk*8];
  const unsigned short* wrow1 = &Ws[(1*16 + lr)*264 + lk*8];
  const unsigned short* wrow2 = &Ws[(2*16 + lr)*264 + lk*8];
  const unsigned short* wrow3 = &Ws[(3*16 + lr)*264 + lk*8];

  int nChunks = N >> 6;
  for (int ch = 0; ch < nChunks; ++ch) {
    int c0 = ch << 6;
    __syncthreads();
#pragma unroll
    for (int it = 0; it < 16; ++it) {
      int l = tid + it*256;
      int row = l >> 6, kq = l & 63;
      float4 v = *(const float4*)(W + (size_t)(c0+row)*256 + kq*4);
      unsigned* dst = (unsigned*)&Ws[row*264 + kq*4];
      dst[0] = packbf(v.x, v.y);
      dst[1] = packbf(v.z, v.w);
    }
    __syncthreads();

    float b0 = bias[c0 + lr], b1 = bias[c0 + 16 + lr];
    float b2 = bias[c0 + 32 + lr], b3 = bias[c0 + 48 + lr];
    f32x4 acc0 = {b0, b0, b0, b0};
    f32x4 acc1 = {b1, b1, b1, b1};
    f32x4 acc2 = {b2, b2, b2, b2};
    f32x4 acc3 = {b3, b3, b3, b3};

#pragma unroll
    for (int ks = 0; ks < 8; ++ks) {
      bf16x8 a  = *(const bf16x8*)(arow  + ks*32);
      bf16x8 q0 = *(const bf16x8*)(wrow0 + ks*32);
      bf16x8 q1 = *(const bf16x8*)(wrow1 + ks*32);
      bf16x8 q2 = *(const bf16x8*)(wrow2 + ks*32);
      bf16x8 q3 = *(const bf16x8*)(wrow3 + ks*32);
      acc0 = __builtin_amdgcn_mfma_f32_16x16x32_bf16(a, q0, acc0, 0, 0, 0);
      acc1 = __builtin_amdgcn_mfma_f32_16x16x32_bf16(a, q1, acc1, 0, 0, 0);
      acc2 = __builtin_amdgcn_mfma_f32_16x16x32_bf16(a, q2, acc2, 0, 0, 0);
      acc3 = __builtin_amdgcn_mfma_f32_16x16x32_bf16(a, q3, acc3, 0, 0, 0);
    }

#pragma unroll
    for (int j = 0; j < 4; ++j) {
      int row = r0 + w*16 + lk*4 + j;
      float* cp = C + (size_t)row * N + c0 + lr;
      cp[0]  = acc0[j];
      cp[16] = acc1[j];
      cp[32] = acc2[j];
      cp[48] = acc3[j];
    }
  }
}

// ---------- K4: MFMA attention, one WG per (b, head). ----------
__global__ __launch_bounds__(256, 1) void attn_mfma_kernel(
    const float* __restrict__ qkv, float* __restrict__ obuf)
{
  int b = blockIdx.x >> 3, h = blockIdx.x & 7;
  int tid = threadIdx.x;
  int lane = tid & 63;
  int w = tid >> 6;
  int lr = lane & 15, lk = lane >> 4;

  __shared__ unsigned short Ks[512*40];   // K rows [s][40] bf16
  __shared__ unsigned short Vt[32*520];   // V^T [d][s'] bf16
  __shared__ unsigned short Sb[64*520];   // P [qrow][s'] bf16 (wave-private rows)
  __shared__ unsigned short Qs[64*40];    // Q tile (wave-private rows)

  for (int l = tid; l < 4096; l += 256) {
    int s = l >> 3, dq = l & 7;
    const float* kr = qkv + ((size_t)s*BB + b)*768 + 256 + h*32 + dq*4;
    float4 kv = *(const float4*)kr;
    unsigned* kd = (unsigned*)&Ks[s*40 + dq*4];
    kd[0] = packbf(kv.x, kv.y);
    kd[1] = packbf(kv.z, kv.w);
    float4 vv = *(const float4*)(kr + 256);
    int sp = ((s & 15) << 5) + (s >> 4);
    Vt[(dq*4+0)*520 + sp] = f2bf(vv.x);
    Vt[(dq*4+1)*520 + sp] = f2bf(vv.y);
    Vt[(dq*4+2)*520 + sp] = f2bf(vv.z);
    Vt[(dq*4+3)*520 + sp] = f2bf(vv.w);
  }
  __syncthreads();

  const float SCL = 0.17677669529663687f;   // 1/sqrt(32)

  for (int p = 0; p < 8; ++p) {
    int q0 = p*64 + w*16;
#pragma unroll
    for (int i = 0; i < 2; ++i) {
      int l = lane + i*64;
      int row = l >> 3, dq = l & 7;
      const float* qr = qkv + ((size_t)(q0+row)*BB + b)*768 + h*32 + dq*4;
      float4 qv = *(const float4*)qr;
      unsigned* qd = (unsigned*)&Qs[(w*16+row)*40 + dq*4];
      qd[0] = packbf(qv.x*SCL, qv.y*SCL);
      qd[1] = packbf(qv.z*SCL, qv.w*SCL);
    }
    bf16x8 a = *(const bf16x8*)&Qs[(w*16+lr)*40 + lk*8];
    f32x4 st[32];
#pragma unroll
    for (int t = 0; t < 32; ++t) {
      bf16x8 kb = *(const bf16x8*)&Ks[(t*16+lr)*40 + lk*8];
      f32x4 z = {0.f, 0.f, 0.f, 0.f};
      st[t] = __builtin_amdgcn_mfma_f32_16x16x32_bf16(a, kb, z, 0, 0, 0);
    }
    float inv[4];
#pragma unroll
    for (int j = 0; j < 4; ++j) {
      float m = -3e38f;
#pragma unroll
      for (int t = 0; t < 32; ++t) m = fmaxf(m, st[t][j]);
      m = fmaxf(m, __shfl_xor(m, 1));
      m = fmaxf(m, __shfl_xor(m, 2));
      m = fmaxf(m, __shfl_xor(m, 4));
      m = fmaxf(m, __shfl_xor(m, 8));
      float sum = 0.f;
#pragma unroll
      for (int t = 0; t < 32; ++t) { float e = __expf(st[t][j] - m); st[t][j] = e; sum += e; }
      sum += __shfl_xor(sum, 1);
      sum += __shfl_xor(sum, 2);
      sum += __shfl_xor(sum, 4);
      sum += __shfl_xor(sum, 8);
      inv[j] = 1.0f / sum;
    }
#pragma unroll
    for (int j = 0; j < 4; ++j) {
      unsigned pk[16];
#pragma unroll
      for (int i = 0; i < 16; ++i)
        pk[i] = packbf(st[2*i][j]*inv[j], st[2*i+1][j]*inv[j]);
      uint4* dst = (uint4*)&Sb[(w*16 + lk*4 + j)*520 + lr*32];
      dst[0] = make_uint4(pk[0], pk[1], pk[2], pk[3]);
      dst[1] = make_uint4(pk[4], pk[5], pk[6], pk[7]);
      dst[2] = make_uint4(pk[8], pk[9], pk[10], pk[11]);
      dst[3] = make_uint4(pk[12], pk[13], pk[14], pk[15]);
    }
    f32x4 o0 = {0.f,0.f,0.f,0.f}, o1 = {0.f,0.f,0.f,0.f};
#pragma unroll
    for (int kt = 0; kt < 16; ++kt) {
      bf16x8 pa = *(const bf16x8*)&Sb[(w*16 + lr)*520 + kt*32 + lk*8];
      bf16x8 v0 = *(const bf16x8*)&Vt[(lr)*520 + kt*32 + lk*8];
      bf16x8 v1 = *(const bf16x8*)&Vt[(16 + lr)*520 + kt*32 + lk*8];
      o0 = __builtin_amdgcn_mfma_f32_16x16x32_bf16(pa, v0, o0, 0, 0, 0);
      o1 = __builtin_amdgcn_mfma_f32_16x16x32_bf16(pa, v1, o1, 0, 0, 0);
    }
#pragma unroll
    for (int j = 0; j < 4; ++j) {
      int q = q0 + lk*4 + j;
      float* op = obuf + ((size_t)q*BB + b)*EE + h*32;
      op[lr]      = o0[j];
      op[16 + lr] = o1[j];
    }
  }
}

// ---------- K5: fuse output weights. Wf = oW @ aWout ; bf = oW @ about + ob ----------
__global__ __launch_bounds__(256) void fuse_w_kernel(
    const float* __restrict__ aWout, const float* __restrict__ about,
    const float* __restrict__ oW, const float* __restrict__ ob,
    float* __restrict__ Wf, float* __restrict__ bf)
{
  int g = blockIdx.x;        // output row 0..63
  int k = threadIdx.x;       // col 0..255
  const float* owr = oW + (size_t)g * 256;
  float acc = 0.f;
  for (int j = 0; j < 256; ++j)
    acc += owr[j] * aWout[(size_t)j * 256 + k];
  Wf[(size_t)g * 256 + k] = acc;
  if (k == 0) {
    float a = ob[g];
    for (int j = 0; j < 256; ++j) a += owr[j] * about[j];
    bf[g] = a;
  }
}

// ---------- K6: imputed = obuf @ Wf.T + bf ; blend ; write both outputs ----------
__global__ __launch_bounds__(256) void final_kernel(
    const float* __restrict__ A,      // obuf [16384][256]
    const float* __restrict__ W,      // Wf [64][256]
    const float* __restrict__ bias,   // bf [64]
    const float* __restrict__ x, const float* __restrict__ mask,
    float* __restrict__ out)          // [output | imputed], each [B][T][D]
{
  __shared__ float As[64*260];
  __shared__ unsigned Ws[64*130];
  int tid = threadIdx.x;
  int ty = tid >> 4, tx = tid & 15;
  int r0 = blockIdx.x * 64;

  for (int l = tid; l < 4096; l += 256) {
    int row = l >> 6, kq = l & 63;
    float4 v = *(const float4*)(A + (size_t)(r0 + row)*256 + kq*4);
    *(float4*)&As[row*260 + kq*4] = v;
  }
  for (int l = tid; l < 4096; l += 256) {
    int c = l >> 6, kq = l & 63;
    float4 v = *(const float4*)(W + (size_t)c*256 + kq*4);
    uint2 p; p.x = packbf(v.x, v.y); p.y = packbf(v.z, v.w);
    *(uint2*)&Ws[c*130 + kq*2] = p;
  }
  __syncthreads();

  float acc[4][4];
#pragma unroll
  for (int rj = 0; rj < 4; rj++)
#pragma unroll
    for (int cj = 0; cj < 4; cj++)
      acc[rj][cj] = bias[tx + 16*cj];

#pragma unroll 2
  for (int kq = 0; kq < 64; kq++) {
    float4 av[4];
#pragma unroll
    for (int rj = 0; rj < 4; rj++)
      av[rj] = *(const float4*)&As[(ty*4+rj)*260 + 4*kq];
#pragma unroll
    for (int cj = 0; cj < 4; cj++) {
      uint2 w2 = *(const uint2*)&Ws[(tx + 16*cj)*130 + 2*kq];
      float w0 = bflo(w2.x), w1 = bfhi(w2.x);
      float w2f = bflo(w2.y), w3 = bfhi(w2.y);
#pragma unroll
      for (int rj = 0; rj < 4; rj++)
        acc[rj][cj] += av[rj].x*w0 + av[rj].y*w1 + av[rj].z*w2f + av[rj].w*w3;
    }
  }

#pragma unroll
  for (int rj = 0; rj < 4; rj++) {
    int r = r0 + ty*4 + rj;
    int t = r >> 5, b = r & 31;
    size_t base = ((size_t)b * TT + t) * DD;
#pragma unroll
    for (int cj = 0; cj < 4; cj++) {
      int c = tx + 16*cj;
      float imp = acc[rj][cj];
      float xv = x[base + c], mv = mask[base + c];
      out[base + c] = xv*mv + imp*(1.0f - mv);
      out[(size_t)1048576 + base + c] = imp;
    }
  }
}

// ---------- launcher ----------
extern "C" void kernel_launch(void* const* d_in, const int* in_sizes, int n_in,
                              void* d_out, int out_size, void* d_ws, size_t ws_size,
                              hipStream_t stream) {
  const float* x     = (const float*)d_in[0];
  const float* mask  = (const float*)d_in[1];
  const float* fWi   = (const float*)d_in[2];
  const float* fbi   = (const float*)d_in[3];
  const float* fWh   = (const float*)d_in[4];
  const float* fbh   = (const float*)d_in[5];
  const float* bWi   = (const float*)d_in[6];
  const float* bbi   = (const float*)d_in[7];
  const float* bWh   = (const float*)d_in[8];
  const float* bbh   = (const float*)d_in[9];
  const float* aWin  = (const float*)d_in[10];
  const float* abin  = (const float*)d_in[11];
  const float* aWout = (const float*)d_in[12];
  const float* about = (const float*)d_in[13];
  const float* oW    = (const float*)d_in[14];
  const float* ob    = (const float*)d_in[15];
  float* out = (float*)d_out;
  float* ws  = (float*)d_ws;

  // workspace layout (f32 elems), aliased across phases:
  // [0, 12582912)        gi [16384][768] -> qkv [16384][768] -> (after attn) Wf[64][256] @0, bf[64] @16384
  // [12582912, 16777216) hc [16384][256] -> obuf [16384][256]
  float* gi   = ws;
  float* hc   = ws + 12582912;
  float* qkv  = ws;
  float* obuf = ws + 12582912;
  float* Wf   = ws;
  float* bf   = ws + 16384;

  gi_mfma_kernel<<<256, 256, 0, stream>>>(x, mask, fWi, fbi, bWi, bbi, gi);
  scan_mfma_kernel<<<4, 256, 0, stream>>>(gi, fWh, fbh, bWh, bbh, hc);
  mfma_gemm_kernel<<<256, 256, 0, stream>>>(hc, aWin, abin, qkv, 768);
  attn_mfma_kernel<<<256, 256, 0, stream>>>(qkv, obuf);
  fuse_w_kernel<<<64, 256, 0, stream>>>(aWout, about, oW, ob, Wf, bf);
  final_kernel<<<256, 256, 0, stream>>>(obuf, Wf, bf, x, mask, out);
}

// Round 14
// 599.340 us; speedup vs baseline: 2.3766x; 2.3766x over previous
//
#include <hip/hip_runtime.h>

#define TT 512
#define BB 32
#define DD 64
#define HH 128
#define EE 256
#define NR 16384   // T*B rows

typedef _Float16 h2v __attribute__((ext_vector_type(2)));
typedef short bf16x8 __attribute__((ext_vector_type(8)));
typedef float f32x4 __attribute__((ext_vector_type(4)));

// ---------- helpers ----------
static __device__ __forceinline__ float bflo(unsigned u){ return __uint_as_float(u << 16); }
static __device__ __forceinline__ float bfhi(unsigned u){ return __uint_as_float(u & 0xFFFF0000u); }
static __device__ __forceinline__ unsigned short f2bf(float x){
  unsigned u = __float_as_uint(x);
  return (unsigned short)((u + 0x7FFFu + ((u >> 16) & 1u)) >> 16);  // RNE
}
static __device__ __forceinline__ unsigned packbf(float a, float b){
  return (unsigned)f2bf(a) | ((unsigned)f2bf(b) << 16);
}
static __device__ __forceinline__ float sigmoidf_(float x){
  return 1.0f / (1.0f + __expf(-x));
}
static __device__ __forceinline__ float tanhf_(float x){
  float e = __expf(2.0f * x);
  return 1.0f - 2.0f / (e + 1.0f);
}
static __device__ __forceinline__ unsigned packh2(float a, float b){
  h2v v; v.x = (_Float16)a; v.y = (_Float16)b;
  return __builtin_bit_cast(unsigned, v);
}
#define BCH(u) __builtin_bit_cast(h2v, (u))
#define DOT2(a, b, c) __builtin_amdgcn_fdot2((a), (b), (c), false)
// LDS-only barrier: don't drain vmcnt (gi prefetch / hc stores stay in flight)
#define LGKM_BARRIER() asm volatile("s_waitcnt lgkmcnt(0)\n\ts_barrier" ::: "memory")

// ---------- K1: MFMA gi. gi[r][c] = bi + xm[r] . Wi_row(c), c in [0,768) (fwd|bwd) ----------
__global__ __launch_bounds__(256) void gi_mfma_kernel(
    const float* __restrict__ x, const float* __restrict__ mask,
    const float* __restrict__ WiF, const float* __restrict__ biF,
    const float* __restrict__ WiB, const float* __restrict__ biB,
    float* __restrict__ gi)
{
  __shared__ unsigned short As[64*72];
  __shared__ unsigned short Ws[64*72];
  int tid = threadIdx.x;
  int r0 = blockIdx.x * 64;
  int lane = tid & 63;
  int w = tid >> 6;
  int lr = lane & 15, lk = lane >> 4;

#pragma unroll
  for (int it = 0; it < 4; ++it) {
    int l = tid + it*256;
    int row = l >> 4, kq = l & 15;
    int r = r0 + row; int t = r >> 5, b = r & 31;
    const float* xr = x + ((size_t)b*TT + t)*DD + kq*4;
    const float* mr = mask + ((size_t)b*TT + t)*DD + kq*4;
    float4 xv = *(const float4*)xr;
    float4 mv = *(const float4*)mr;
    unsigned* dst = (unsigned*)&As[row*72 + kq*4];
    dst[0] = packbf(xv.x*mv.x, xv.y*mv.y);
    dst[1] = packbf(xv.z*mv.z, xv.w*mv.w);
  }

  for (int ch = 0; ch < 12; ++ch) {
    int c0 = ch * 64;
    __syncthreads();
#pragma unroll
    for (int it = 0; it < 4; ++it) {
      int l = tid + it*256;
      int col = l >> 4, kq = l & 15;
      int c = c0 + col;
      const float* wr = (c < 384 ? WiF + (size_t)c*64 : WiB + (size_t)(c-384)*64) + kq*4;
      float4 v = *(const float4*)wr;
      unsigned* dst = (unsigned*)&Ws[col*72 + kq*4];
      dst[0] = packbf(v.x, v.y);
      dst[1] = packbf(v.z, v.w);
    }
    __syncthreads();

    const unsigned short* arow = &As[(w*16 + lr)*72 + lk*8];
    f32x4 acc[4];
#pragma unroll
    for (int ct = 0; ct < 4; ++ct) {
      int cg = c0 + ct*16 + lr;
      float bv = (cg < 384) ? biF[cg] : biB[cg - 384];
      acc[ct][0] = bv; acc[ct][1] = bv; acc[ct][2] = bv; acc[ct][3] = bv;
    }
#pragma unroll
    for (int ks = 0; ks < 2; ++ks) {
      bf16x8 a = *(const bf16x8*)(arow + ks*32);
#pragma unroll
      for (int ct = 0; ct < 4; ++ct) {
        bf16x8 wv = *(const bf16x8*)&Ws[(ct*16 + lr)*72 + lk*8 + ks*32];
        acc[ct] = __builtin_amdgcn_mfma_f32_16x16x32_bf16(a, wv, acc[ct], 0, 0, 0);
      }
    }
#pragma unroll
    for (int ct = 0; ct < 4; ++ct) {
#pragma unroll
      for (int j = 0; j < 4; ++j) {
        int row = r0 + w*16 + lk*4 + j;
        gi[(size_t)row*768 + c0 + ct*16 + lr] = acc[ct][j];
      }
    }
  }
}

// ---------- K2: GRU scan (R9 version — best known, 457us). ----------
__global__ __launch_bounds__(256)
__attribute__((amdgpu_waves_per_eu(1, 1)))
void scan_kernel(
    const float* __restrict__ gi,      // [16384][768]
    const float* __restrict__ WhF, const float* __restrict__ bhF,
    const float* __restrict__ WhB, const float* __restrict__ bhB,
    float* __restrict__ hc)
{
  int dir = blockIdx.x >> 5;
  int b = blockIdx.x & 31;
  const float* Wh = dir ? WhB : WhF;
  const float* bh = dir ? bhB : bhF;
  int tid = threadIdx.x;
  int j2 = tid >> 1, h2 = tid & 1;

  __shared__ __align__(16) float h_s[128];
  __shared__ __align__(16) unsigned hs16[68];       // f16 h pairs: halves at 0 / 36
  __shared__ __align__(16) unsigned rh16[76];       // f16 rh pairs: quarters at 0/20/40/60
  __shared__ float z_s[128];

  const float* wp1 = Wh + (size_t)tid * 128;
#define LDA(n) unsigned A##n = packh2(wp1[2*(n)], wp1[2*(n)+1]);
  LDA(0) LDA(1) LDA(2) LDA(3) LDA(4) LDA(5) LDA(6) LDA(7)
  LDA(8) LDA(9) LDA(10) LDA(11) LDA(12) LDA(13) LDA(14) LDA(15)
  LDA(16) LDA(17) LDA(18) LDA(19) LDA(20) LDA(21) LDA(22) LDA(23)
  LDA(24) LDA(25) LDA(26) LDA(27) LDA(28) LDA(29) LDA(30) LDA(31)
  LDA(32) LDA(33) LDA(34) LDA(35) LDA(36) LDA(37) LDA(38) LDA(39)
  LDA(40) LDA(41) LDA(42) LDA(43) LDA(44) LDA(45) LDA(46) LDA(47)
  LDA(48) LDA(49) LDA(50) LDA(51) LDA(52) LDA(53) LDA(54) LDA(55)
  LDA(56) LDA(57) LDA(58) LDA(59) LDA(60) LDA(61) LDA(62) LDA(63)
#undef LDA
  const float* wp2 = Wh + (size_t)(256 + j2) * 128 + h2 * 64;
#define LDB(n) unsigned B##n = packh2(wp2[2*(n)], wp2[2*(n)+1]);
  LDB(0) LDB(1) LDB(2) LDB(3) LDB(4) LDB(5) LDB(6) LDB(7)
  LDB(8) LDB(9) LDB(10) LDB(11) LDB(12) LDB(13) LDB(14) LDB(15)
  LDB(16) LDB(17) LDB(18) LDB(19) LDB(20) LDB(21) LDB(22) LDB(23)
  LDB(24) LDB(25) LDB(26) LDB(27) LDB(28) LDB(29) LDB(30) LDB(31)
#undef LDB

  float bh1 = bh[tid];
  float bh2 = bh[256 + j2];

  if (tid < 128) h_s[tid] = 0.0f;
  if (tid < 68)  hs16[tid] = 0u;
  __syncthreads();

  size_t row0 = dir ? ((size_t)(TT-1)*BB + b) : (size_t)b;
  const float* grow = gi + row0 * 768 + dir * 384;
  long dstep = (dir ? -(long)BB : (long)BB) * 768;
  float gi1v = grow[tid];
  float gi2v = grow[256 + j2];

  for (int s = 0; s < TT; s++) {
#define PIN8(a,b_,c,d,e,f,g,hh) asm volatile("" : "+v"(a), "+v"(b_), "+v"(c), "+v"(d), "+v"(e), "+v"(f), "+v"(g), "+v"(hh));
    PIN8(A0,A1,A2,A3,A4,A5,A6,A7)
    PIN8(A8,A9,A10,A11,A12,A13,A14,A15)
    PIN8(A16,A17,A18,A19,A20,A21,A22,A23)
    PIN8(A24,A25,A26,A27,A28,A29,A30,A31)
    PIN8(A32,A33,A34,A35,A36,A37,A38,A39)
    PIN8(A40,A41,A42,A43,A44,A45,A46,A47)
    PIN8(A48,A49,A50,A51,A52,A53,A54,A55)
    PIN8(A56,A57,A58,A59,A60,A61,A62,A63)
    PIN8(B0,B1,B2,B3,B4,B5,B6,B7)
    PIN8(B8,B9,B10,B11,B12,B13,B14,B15)
    PIN8(B16,B17,B18,B19,B20,B21,B22,B23)
    PIN8(B24,B25,B26,B27,B28,B29,B30,B31)
#undef PIN8

    const float* gnext = grow + dstep;
    float gi1n = 0.f, gi2n = 0.f;
    if (s + 1 < TT) { gi1n = gnext[tid]; gi2n = gnext[256 + j2]; }

    float hold = h_s[tid & 127];

    const unsigned* hp0 = hs16;
    const unsigned* hp1 = hs16 + 36;
    float ya = 0.f, yb = 0.f, yc = 0.f, yd = 0.f;
#define S1(n, base, w0, w1, w2, w3) { uint4 hv = *(const uint4*)((base) + 4*(n)); \
    ya = DOT2(BCH(w0), BCH(hv.x), ya); yb = DOT2(BCH(w1), BCH(hv.y), yb); \
    yc = DOT2(BCH(w2), BCH(hv.z), yc); yd = DOT2(BCH(w3), BCH(hv.w), yd); }
    S1(0, hp0, A0,A1,A2,A3)     S1(1, hp0, A4,A5,A6,A7)
    S1(2, hp0, A8,A9,A10,A11)   S1(3, hp0, A12,A13,A14,A15)
    S1(4, hp0, A16,A17,A18,A19) S1(5, hp0, A20,A21,A22,A23)
    S1(6, hp0, A24,A25,A26,A27) S1(7, hp0, A28,A29,A30,A31)
    S1(0, hp1, A32,A33,A34,A35) S1(1, hp1, A36,A37,A38,A39)
    S1(2, hp1, A40,A41,A42,A43) S1(3, hp1, A44,A45,A46,A47)
    S1(4, hp1, A48,A49,A50,A51) S1(5, hp1, A52,A53,A54,A55)
    S1(6, hp1, A56,A57,A58,A59) S1(7, hp1, A60,A61,A62,A63)
#undef S1
    float y = (ya + yb) + (yc + yd);
    float sg = sigmoidf_(gi1v + y + bh1);
    float rhv = sg * hold;
    float rhp = __shfl_xor(rhv, 1);
    if (tid < 128) {
      if ((tid & 1) == 0) {
        int pi = tid >> 1;
        rh16[(pi & 15) + 20 * (pi >> 4)] = packh2(rhv, rhp);
      }
    } else {
      z_s[tid - 128] = sg;
    }
    LGKM_BARRIER();   // barrier A: rh/z visible

    const unsigned* rp0 = rh16 + h2 * 40;
    const unsigned* rp1 = rp0 + 20;
    float ca = 0.f, cb = 0.f, cc = 0.f, cd = 0.f;
#define S2(n, base, w0, w1, w2, w3) { uint4 rv = *(const uint4*)((base) + 4*(n)); \
    ca = DOT2(BCH(w0), BCH(rv.x), ca); cb = DOT2(BCH(w1), BCH(rv.y), cb); \
    cc = DOT2(BCH(w2), BCH(rv.z), cc); cd = DOT2(BCH(w3), BCH(rv.w), cd); }
    S2(0, rp0, B0,B1,B2,B3)     S2(1, rp0, B4,B5,B6,B7)
    S2(2, rp0, B8,B9,B10,B11)   S2(3, rp0, B12,B13,B14,B15)
    S2(0, rp1, B16,B17,B18,B19) S2(1, rp1, B20,B21,B22,B23)
    S2(2, rp1, B24,B25,B26,B27) S2(3, rp1, B28,B29,B30,B31)
#undef S2
    float y2 = (ca + cb) + (cc + cd);
    y2 += __shfl_xor(y2, 1);
    float nn = tanhf_(gi2v + y2 + bh2);
    float zv = z_s[j2];
    float hv_ = h_s[j2];
    float hn = nn + zv * (hv_ - nn);
    float hnp = __shfl_xor(hn, 2);
    if (h2 == 0) {
      h_s[j2] = hn;
      int t = dir ? (TT - 1 - s) : s;
      hc[((size_t)t * BB + b) * EE + dir * HH + j2] = hn;
    }
    if ((tid & 3) == 0) {
      int pi = tid >> 2;
      hs16[(pi & 31) + 36 * (j2 >> 6)] = packh2(hn, hnp);
    }
    LGKM_BARRIER();   // barrier B: h visible
    gi1v = gi1n; gi2v = gi2n;
    grow = gnext;
  }
}

// ---------- K3: MFMA GEMM. C[r][c] = bias[c] + sum_k A[r][k]*W[c][k], K=256 ----------
__global__ __launch_bounds__(256) void mfma_gemm_kernel(
    const float* __restrict__ A, const float* __restrict__ W,
    const float* __restrict__ bias, float* __restrict__ C,
    int N)
{
  __shared__ unsigned short As[64*264];
  __shared__ unsigned short Ws[64*264];
  int tid = threadIdx.x;
  int r0 = blockIdx.x * 64;
  int lane = tid & 63;
  int w = tid >> 6;
  int lr = lane & 15;
  int lk = lane >> 4;

#pragma unroll
  for (int it = 0; it < 16; ++it) {
    int l = tid + it*256;
    int row = l >> 6, kq = l & 63;
    float4 v = *(const float4*)(A + (size_t)(r0+row)*256 + kq*4);
    unsigned* dst = (unsigned*)&As[row*264 + kq*4];
    dst[0] = packbf(v.x, v.y);
    dst[1] = packbf(v.z, v.w);
  }

  const unsigned short* arow = &As[(w*16 + lr)*264 + lk*8];
  const unsigned short* wrow0 = &Ws[(0*16 + lr)*264 + lk*8];
  const unsigned short* wrow1 = &Ws[(1*16 + lr)*264 + lk*8];
  const unsigned short* wrow2 = &Ws[(2*16 + lr)*264 + lk*8];
  const unsigned short* wrow3 = &Ws[(3*16 + lr)*264 + lk*8];

  int nChunks = N >> 6;
  for (int ch = 0; ch < nChunks; ++ch) {
    int c0 = ch << 6;
    __syncthreads();
#pragma unroll
    for (int it = 0; it < 16; ++it) {
      int l = tid + it*256;
      int row = l >> 6, kq = l & 63;
      float4 v = *(const float4*)(W + (size_t)(c0+row)*256 + kq*4);
      unsigned* dst = (unsigned*)&Ws[row*264 + kq*4];
      dst[0] = packbf(v.x, v.y);
      dst[1] = packbf(v.z, v.w);
    }
    __syncthreads();

    float b0 = bias[c0 + lr], b1 = bias[c0 + 16 + lr];
    float b2 = bias[c0 + 32 + lr], b3 = bias[c0 + 48 + lr];
    f32x4 acc0 = {b0, b0, b0, b0};
    f32x4 acc1 = {b1, b1, b1, b1};
    f32x4 acc2 = {b2, b2, b2, b2};
    f32x4 acc3 = {b3, b3, b3, b3};

#pragma unroll
    for (int ks = 0; ks < 8; ++ks) {
      bf16x8 a  = *(const bf16x8*)(arow  + ks*32);
      bf16x8 q0 = *(const bf16x8*)(wrow0 + ks*32);
      bf16x8 q1 = *(const bf16x8*)(wrow1 + ks*32);
      bf16x8 q2 = *(const bf16x8*)(wrow2 + ks*32);
      bf16x8 q3 = *(const bf16x8*)(wrow3 + ks*32);
      acc0 = __builtin_amdgcn_mfma_f32_16x16x32_bf16(a, q0, acc0, 0, 0, 0);
      acc1 = __builtin_amdgcn_mfma_f32_16x16x32_bf16(a, q1, acc1, 0, 0, 0);
      acc2 = __builtin_amdgcn_mfma_f32_16x16x32_bf16(a, q2, acc2, 0, 0, 0);
      acc3 = __builtin_amdgcn_mfma_f32_16x16x32_bf16(a, q3, acc3, 0, 0, 0);
    }

#pragma unroll
    for (int j = 0; j < 4; ++j) {
      int row = r0 + w*16 + lk*4 + j;
      float* cp = C + (size_t)row * N + c0 + lr;
      cp[0]  = acc0[j];
      cp[16] = acc1[j];
      cp[32] = acc2[j];
      cp[48] = acc3[j];
    }
  }
}

// ---------- K4: MFMA attention, one WG per (b, head). ----------
__global__ __launch_bounds__(256, 1) void attn_mfma_kernel(
    const float* __restrict__ qkv, float* __restrict__ obuf)
{
  int b = blockIdx.x >> 3, h = blockIdx.x & 7;
  int tid = threadIdx.x;
  int lane = tid & 63;
  int w = tid >> 6;
  int lr = lane & 15, lk = lane >> 4;

  __shared__ unsigned short Ks[512*40];   // K rows [s][40] bf16
  __shared__ unsigned short Vt[32*520];   // V^T [d][s'] bf16
  __shared__ unsigned short Sb[64*520];   // P [qrow][s'] bf16 (wave-private rows)
  __shared__ unsigned short Qs[64*40];    // Q tile (wave-private rows)

  for (int l = tid; l < 4096; l += 256) {
    int s = l >> 3, dq = l & 7;
    const float* kr = qkv + ((size_t)s*BB + b)*768 + 256 + h*32 + dq*4;
    float4 kv = *(const float4*)kr;
    unsigned* kd = (unsigned*)&Ks[s*40 + dq*4];
    kd[0] = packbf(kv.x, kv.y);
    kd[1] = packbf(kv.z, kv.w);
    float4 vv = *(const float4*)(kr + 256);
    int sp = ((s & 15) << 5) + (s >> 4);
    Vt[(dq*4+0)*520 + sp] = f2bf(vv.x);
    Vt[(dq*4+1)*520 + sp] = f2bf(vv.y);
    Vt[(dq*4+2)*520 + sp] = f2bf(vv.z);
    Vt[(dq*4+3)*520 + sp] = f2bf(vv.w);
  }
  __syncthreads();

  const float SCL = 0.17677669529663687f;   // 1/sqrt(32)

  for (int p = 0; p < 8; ++p) {
    int q0 = p*64 + w*16;
#pragma unroll
    for (int i = 0; i < 2; ++i) {
      int l = lane + i*64;
      int row = l >> 3, dq = l & 7;
      const float* qr = qkv + ((size_t)(q0+row)*BB + b)*768 + h*32 + dq*4;
      float4 qv = *(const float4*)qr;
      unsigned* qd = (unsigned*)&Qs[(w*16+row)*40 + dq*4];
      qd[0] = packbf(qv.x*SCL, qv.y*SCL);
      qd[1] = packbf(qv.z*SCL, qv.w*SCL);
    }
    bf16x8 a = *(const bf16x8*)&Qs[(w*16+lr)*40 + lk*8];
    f32x4 st[32];
#pragma unroll
    for (int t = 0; t < 32; ++t) {
      bf16x8 kb = *(const bf16x8*)&Ks[(t*16+lr)*40 + lk*8];
      f32x4 z = {0.f, 0.f, 0.f, 0.f};
      st[t] = __builtin_amdgcn_mfma_f32_16x16x32_bf16(a, kb, z, 0, 0, 0);
    }
    float inv[4];
#pragma unroll
    for (int j = 0; j < 4; ++j) {
      float m = -3e38f;
#pragma unroll
      for (int t = 0; t < 32; ++t) m = fmaxf(m, st[t][j]);
      m = fmaxf(m, __shfl_xor(m, 1));
      m = fmaxf(m, __shfl_xor(m, 2));
      m = fmaxf(m, __shfl_xor(m, 4));
      m = fmaxf(m, __shfl_xor(m, 8));
      float sum = 0.f;
#pragma unroll
      for (int t = 0; t < 32; ++t) { float e = __expf(st[t][j] - m); st[t][j] = e; sum += e; }
      sum += __shfl_xor(sum, 1);
      sum += __shfl_xor(sum, 2);
      sum += __shfl_xor(sum, 4);
      sum += __shfl_xor(sum, 8);
      inv[j] = 1.0f / sum;
    }
#pragma unroll
    for (int j = 0; j < 4; ++j) {
      unsigned pk[16];
#pragma unroll
      for (int i = 0; i < 16; ++i)
        pk[i] = packbf(st[2*i][j]*inv[j], st[2*i+1][j]*inv[j]);
      uint4* dst = (uint4*)&Sb[(w*16 + lk*4 + j)*520 + lr*32];
      dst[0] = make_uint4(pk[0], pk[1], pk[2], pk[3]);
      dst[1] = make_uint4(pk[4], pk[5], pk[6], pk[7]);
      dst[2] = make_uint4(pk[8], pk[9], pk[10], pk[11]);
      dst[3] = make_uint4(pk[12], pk[13], pk[14], pk[15]);
    }
    f32x4 o0 = {0.f,0.f,0.f,0.f}, o1 = {0.f,0.f,0.f,0.f};
#pragma unroll
    for (int kt = 0; kt < 16; ++kt) {
      bf16x8 pa = *(const bf16x8*)&Sb[(w*16 + lr)*520 + kt*32 + lk*8];
      bf16x8 v0 = *(const bf16x8*)&Vt[(lr)*520 + kt*32 + lk*8];
      bf16x8 v1 = *(const bf16x8*)&Vt[(16 + lr)*520 + kt*32 + lk*8];
      o0 = __builtin_amdgcn_mfma_f32_16x16x32_bf16(pa, v0, o0, 0, 0, 0);
      o1 = __builtin_amdgcn_mfma_f32_16x16x32_bf16(pa, v1, o1, 0, 0, 0);
    }
#pragma unroll
    for (int j = 0; j < 4; ++j) {
      int q = q0 + lk*4 + j;
      float* op = obuf + ((size_t)q*BB + b)*EE + h*32;
      op[lr]      = o0[j];
      op[16 + lr] = o1[j];
    }
  }
}

// ---------- K5: fuse output weights. Wf = oW @ aWout ; bf = oW @ about + ob ----------
__global__ __launch_bounds__(256) void fuse_w_kernel(
    const float* __restrict__ aWout, const float* __restrict__ about,
    const float* __restrict__ oW, const float* __restrict__ ob,
    float* __restrict__ Wf, float* __restrict__ bf)
{
  int g = blockIdx.x;        // output row 0..63
  int k = threadIdx.x;       // col 0..255
  const float* owr = oW + (size_t)g * 256;
  float acc = 0.f;
  for (int j = 0; j < 256; ++j)
    acc += owr[j] * aWout[(size_t)j * 256 + k];
  Wf[(size_t)g * 256 + k] = acc;
  if (k == 0) {
    float a = ob[g];
    for (int j = 0; j < 256; ++j) a += owr[j] * about[j];
    bf[g] = a;
  }
}

// ---------- K6: imputed = obuf @ Wf.T + bf ; blend ; write both outputs ----------
__global__ __launch_bounds__(256) void final_kernel(
    const float* __restrict__ A,      // obuf [16384][256]
    const float* __restrict__ W,      // Wf [64][256]
    const float* __restrict__ bias,   // bf [64]
    const float* __restrict__ x, const float* __restrict__ mask,
    float* __restrict__ out)          // [output | imputed], each [B][T][D]
{
  __shared__ float As[64*260];
  __shared__ unsigned Ws[64*130];
  int tid = threadIdx.x;
  int ty = tid >> 4, tx = tid & 15;
  int r0 = blockIdx.x * 64;

  for (int l = tid; l < 4096; l += 256) {
    int row = l >> 6, kq = l & 63;
    float4 v = *(const float4*)(A + (size_t)(r0 + row)*256 + kq*4);
    *(float4*)&As[row*260 + kq*4] = v;
  }
  for (int l = tid; l < 4096; l += 256) {
    int c = l >> 6, kq = l & 63;
    float4 v = *(const float4*)(W + (size_t)c*256 + kq*4);
    uint2 p; p.x = packbf(v.x, v.y); p.y = packbf(v.z, v.w);
    *(uint2*)&Ws[c*130 + kq*2] = p;
  }
  __syncthreads();

  float acc[4][4];
#pragma unroll
  for (int rj = 0; rj < 4; rj++)
#pragma unroll
    for (int cj = 0; cj < 4; cj++)
      acc[rj][cj] = bias[tx + 16*cj];

#pragma unroll 2
  for (int kq = 0; kq < 64; kq++) {
    float4 av[4];
#pragma unroll
    for (int rj = 0; rj < 4; rj++)
      av[rj] = *(const float4*)&As[(ty*4+rj)*260 + 4*kq];
#pragma unroll
    for (int cj = 0; cj < 4; cj++) {
      uint2 w2 = *(const uint2*)&Ws[(tx + 16*cj)*130 + 2*kq];
      float w0 = bflo(w2.x), w1 = bfhi(w2.x);
      float w2f = bflo(w2.y), w3 = bfhi(w2.y);
#pragma unroll
      for (int rj = 0; rj < 4; rj++)
        acc[rj][cj] += av[rj].x*w0 + av[rj].y*w1 + av[rj].z*w2f + av[rj].w*w3;
    }
  }

#pragma unroll
  for (int rj = 0; rj < 4; rj++) {
    int r = r0 + ty*4 + rj;
    int t = r >> 5, b = r & 31;
    size_t base = ((size_t)b * TT + t) * DD;
#pragma unroll
    for (int cj = 0; cj < 4; cj++) {
      int c = tx + 16*cj;
      float imp = acc[rj][cj];
      float xv = x[base + c], mv = mask[base + c];
      out[base + c] = xv*mv + imp*(1.0f - mv);
      out[(size_t)1048576 + base + c] = imp;
    }
  }
}

// ---------- launcher ----------
extern "C" void kernel_launch(void* const* d_in, const int* in_sizes, int n_in,
                              void* d_out, int out_size, void* d_ws, size_t ws_size,
                              hipStream_t stream) {
  const float* x     = (const float*)d_in[0];
  const float* mask  = (const float*)d_in[1];
  const float* fWi   = (const float*)d_in[2];
  const float* fbi   = (const float*)d_in[3];
  const float* fWh   = (const float*)d_in[4];
  const float* fbh   = (const float*)d_in[5];
  const float* bWi   = (const float*)d_in[6];
  const float* bbi   = (const float*)d_in[7];
  const float* bWh   = (const float*)d_in[8];
  const float* bbh   = (const float*)d_in[9];
  const float* aWin  = (const float*)d_in[10];
  const float* abin  = (const float*)d_in[11];
  const float* aWout = (const float*)d_in[12];
  const float* about = (const float*)d_in[13];
  const float* oW    = (const float*)d_in[14];
  const float* ob    = (const float*)d_in[15];
  float* out = (float*)d_out;
  float* ws  = (float*)d_ws;

  // workspace layout (f32 elems), aliased across phases:
  // [0, 12582912)        gi [16384][768] -> qkv [16384][768] -> (after attn) Wf[64][256] @0, bf[64] @16384
  // [12582912, 16777216) hc [16384][256] -> obuf [16384][256]
  float* gi   = ws;
  float* hc   = ws + 12582912;
  float* qkv  = ws;
  float* obuf = ws + 12582912;
  float* Wf   = ws;
  float* bf   = ws + 16384;

  gi_mfma_kernel<<<256, 256, 0, stream>>>(x, mask, fWi, fbi, bWi, bbi, gi);
  scan_kernel<<<64, 256, 0, stream>>>(gi, fWh, fbh, bWh, bbh, hc);
  mfma_gemm_kernel<<<256, 256, 0, stream>>>(hc, aWin, abin, qkv, 768);
  attn_mfma_kernel<<<256, 256, 0, stream>>>(qkv, obuf);
  fuse_w_kernel<<<64, 256, 0, stream>>>(aWout, about, oW, ob, Wf, bf);
  final_kernel<<<256, 256, 0, stream>>>(obuf, Wf, bf, x, mask, out);
}